// Round 18
// baseline (346.202 us; speedup 1.0000x reference)
//
#include <hip/hip_runtime.h>

// GCN 4 layers: N=100000, E=1600000, dims 256->128->64->16->40.
//  colr[N][68]: int[0]=in-degree counter, int[4..68)=up to 64 neighbor ids.
//    Hist writes counter(atomic)+entry into the SAME row -> ~1.25 scattered
//    sectors/edge instead of 2 (degI and colp were separate random lines).
//  A: {proj1 P1=x@W1 bf16} || {degO all + colr fill d<NSPLIT}   (f=0.5)
//  B: {FUSED gather_l1+proj_l2 n<NSPLIT} || {colr fill d>=NSPLIT}
//  C: FUSED gather_l1+proj_l2 [NSPLIT,N)   (h1 stays in regs; P2=(h1@W2)*nS
//     via 16-step shfl-ring GEMM, W2 f32 in LDS; P2 -> separate buffer)
//  L2 tail: FUSED gather P2 + h2 + P3=(h2*nS)@W3;  L3: gather P3 -> t4
//  L4: FUSED gather t4 + (agg@W4)*nD+b4 -> out
// Norms inline rsqrt(max(deg,1)). CAP=64 (Poisson(16): P(deg>=64)~1e-20).

typedef unsigned short ushort_t;
#define CAP  64
#define CAPR 68   // row stride in ints: [0]=cnt, [1..3] pad, [4..67] entries

__device__ __forceinline__ void gload_lds16(const float4* g, float4* l) {
    __builtin_amdgcn_global_load_lds(
        (const __attribute__((address_space(1))) void*)g,
        (__attribute__((address_space(3))) void*)l, 16, 0, 0);
}

__device__ __forceinline__ ushort_t f2bf(float f) {
    unsigned u = __float_as_uint(f);
    u += 0x7FFFu + ((u >> 16) & 1u);          // RNE
    return (ushort_t)(u >> 16);
}
__device__ __forceinline__ float nrm_of(int d) {
    return rsqrtf((float)(d > 1 ? d : 1));
}
#define BFLO(u) __uint_as_float((u) << 16)
#define BFHI(u) __uint_as_float((u) & 0xffff0000u)

// ---------------- proj GEMM body for L1 (f32 in, global_load_lds staged) ------
template<int DIN, int DOUT, int RB, int KT, typename EPI>
__device__ __forceinline__ void proj_body(
        const float* __restrict__ in, const float* __restrict__ W,
        int N, int n0, float4* __restrict__ wlds, float4* __restrict__ xlds,
        EPI&& epi) {
    constexpr int CG  = DOUT / 4;
    constexpr int RPP = 256 / CG;
    constexpr int R4  = RB / RPP;
    constexpr int K4T = KT / 4;
    constexpr int NKT = DIN / KT;
    constexpr int XTILE = RB * K4T;
    constexpr int WTILE = KT * CG;

    const int tid  = threadIdx.x;
    const int wave = tid >> 6;
    const int lane = tid & 63;
    const int rp   = tid / CG;
    const int cg   = tid - rp * CG;

    float4 acc[R4];
#pragma unroll
    for (int r = 0; r < R4; ++r) acc[r] = make_float4(0.f, 0.f, 0.f, 0.f);

    for (int kt = 0; kt < NKT; ++kt) {
        const float4* wsrc = (const float4*)(W + (size_t)kt * KT * DOUT);
#pragma unroll
        for (int j = 0; j < WTILE / 256; ++j) {
            int base = j * 256 + wave * 64;
            gload_lds16(wsrc + base + lane, &wlds[base]);
        }
#pragma unroll
        for (int j = 0; j < XTILE / 256; ++j) {
            int base = j * 256 + wave * 64;
            int fi   = base + lane;
            int row  = fi / K4T;
            int k4   = fi - row * K4T;
            int k4s  = k4 ^ (row & (K4T - 1));
            int grow = n0 + row; if (grow >= N) grow = N - 1;
            const float4* gsrc = (const float4*)(in + (size_t)grow * DIN) + kt * K4T + k4s;
            gload_lds16(gsrc, &xlds[base]);
        }
        __syncthreads();
#pragma unroll 2
        for (int k4 = 0; k4 < K4T; ++k4) {
            float4 w0 = wlds[(k4 * 4 + 0) * CG + cg];
            float4 w1 = wlds[(k4 * 4 + 1) * CG + cg];
            float4 w2 = wlds[(k4 * 4 + 2) * CG + cg];
            float4 w3 = wlds[(k4 * 4 + 3) * CG + cg];
#pragma unroll
            for (int r = 0; r < R4; ++r) {
                int row = rp + r * RPP;
                float4 xv = xlds[row * K4T + (k4 ^ (row & (K4T - 1)))];
                acc[r].x = fmaf(xv.x, w0.x, acc[r].x);
                acc[r].y = fmaf(xv.x, w0.y, acc[r].y);
                acc[r].z = fmaf(xv.x, w0.z, acc[r].z);
                acc[r].w = fmaf(xv.x, w0.w, acc[r].w);
                acc[r].x = fmaf(xv.y, w1.x, acc[r].x);
                acc[r].y = fmaf(xv.y, w1.y, acc[r].y);
                acc[r].z = fmaf(xv.y, w1.z, acc[r].z);
                acc[r].w = fmaf(xv.y, w1.w, acc[r].w);
                acc[r].x = fmaf(xv.z, w2.x, acc[r].x);
                acc[r].y = fmaf(xv.z, w2.y, acc[r].y);
                acc[r].z = fmaf(xv.z, w2.z, acc[r].z);
                acc[r].w = fmaf(xv.z, w2.w, acc[r].w);
                acc[r].x = fmaf(xv.w, w3.x, acc[r].x);
                acc[r].y = fmaf(xv.w, w3.y, acc[r].y);
                acc[r].z = fmaf(xv.w, w3.z, acc[r].z);
                acc[r].w = fmaf(xv.w, w3.w, acc[r].w);
            }
        }
        __syncthreads();
    }
    epi(acc, rp, cg);
}

// ------ FUSED L1-gather + L2-proj body ---------------------------------------
__device__ __forceinline__ void gl1p2_body(
        int n, int cb, int gb, const int* __restrict__ colr,
        const int* __restrict__ degO, const ushort_t* __restrict__ p1bf,
        const float* __restrict__ b1, const float* __restrict__ w2s,
        ushort_t* __restrict__ p2bf) {
    constexpr int DOUT = 128;
    const int* cl = colr + (size_t)n * CAPR;
    int dgi = cl[0];
    int dg = dgi > CAP ? CAP : dgi;
    float acc[8];
#pragma unroll
    for (int k = 0; k < 8; ++k) acc[k] = 0.f;
    int i = 0;
    for (; i + 4 <= dg; i += 4) {
        int4 ss = *(const int4*)(cl + 4 + i);
        uint4 v0 = *(const uint4*)(p1bf + (size_t)ss.x * DOUT + cb * 8);
        uint4 v1 = *(const uint4*)(p1bf + (size_t)ss.y * DOUT + cb * 8);
        uint4 v2 = *(const uint4*)(p1bf + (size_t)ss.z * DOUT + cb * 8);
        uint4 v3 = *(const uint4*)(p1bf + (size_t)ss.w * DOUT + cb * 8);
        float n0 = nrm_of(degO[ss.x]), n1 = nrm_of(degO[ss.y]);
        float n2 = nrm_of(degO[ss.z]), n3 = nrm_of(degO[ss.w]);
        acc[0] = fmaf(n0, BFLO(v0.x), fmaf(n1, BFLO(v1.x), fmaf(n2, BFLO(v2.x), fmaf(n3, BFLO(v3.x), acc[0]))));
        acc[1] = fmaf(n0, BFHI(v0.x), fmaf(n1, BFHI(v1.x), fmaf(n2, BFHI(v2.x), fmaf(n3, BFHI(v3.x), acc[1]))));
        acc[2] = fmaf(n0, BFLO(v0.y), fmaf(n1, BFLO(v1.y), fmaf(n2, BFLO(v2.y), fmaf(n3, BFLO(v3.y), acc[2]))));
        acc[3] = fmaf(n0, BFHI(v0.y), fmaf(n1, BFHI(v1.y), fmaf(n2, BFHI(v2.y), fmaf(n3, BFHI(v3.y), acc[3]))));
        acc[4] = fmaf(n0, BFLO(v0.z), fmaf(n1, BFLO(v1.z), fmaf(n2, BFLO(v2.z), fmaf(n3, BFLO(v3.z), acc[4]))));
        acc[5] = fmaf(n0, BFHI(v0.z), fmaf(n1, BFHI(v1.z), fmaf(n2, BFHI(v2.z), fmaf(n3, BFHI(v3.z), acc[5]))));
        acc[6] = fmaf(n0, BFLO(v0.w), fmaf(n1, BFLO(v1.w), fmaf(n2, BFLO(v2.w), fmaf(n3, BFLO(v3.w), acc[6]))));
        acc[7] = fmaf(n0, BFHI(v0.w), fmaf(n1, BFHI(v1.w), fmaf(n2, BFHI(v2.w), fmaf(n3, BFHI(v3.w), acc[7]))));
    }
    for (; i < dg; ++i) {
        int s0 = cl[4 + i];
        uint4 v0 = *(const uint4*)(p1bf + (size_t)s0 * DOUT + cb * 8);
        float ns0 = nrm_of(degO[s0]);
        acc[0] = fmaf(ns0, BFLO(v0.x), acc[0]);
        acc[1] = fmaf(ns0, BFHI(v0.x), acc[1]);
        acc[2] = fmaf(ns0, BFLO(v0.y), acc[2]);
        acc[3] = fmaf(ns0, BFHI(v0.y), acc[3]);
        acc[4] = fmaf(ns0, BFLO(v0.z), acc[4]);
        acc[5] = fmaf(ns0, BFHI(v0.z), acc[5]);
        acc[6] = fmaf(ns0, BFLO(v0.w), acc[6]);
        acc[7] = fmaf(ns0, BFHI(v0.w), acc[7]);
    }
    float nm = nrm_of(dgi);
    const float* bp = b1 + cb * 8;
    float o[8];
#pragma unroll
    for (int k = 0; k < 8; ++k) o[k] = fmaxf(fmaf(acc[k], nm, bp[k]), 0.f);

    float y0 = 0.f, y1 = 0.f, y2 = 0.f, y3 = 0.f;
    for (int k8 = 0; k8 < 16; ++k8) {
#pragma unroll
        for (int j = 0; j < 8; ++j) {
            float v = __shfl(o[j], gb + k8, 64);
            const float4 w = *(const float4*)(w2s + (k8 * 8 + j) * 64 + cb * 4);
            y0 = fmaf(v, w.x, y0);
            y1 = fmaf(v, w.y, y1);
            y2 = fmaf(v, w.z, y2);
            y3 = fmaf(v, w.w, y3);
        }
    }
    float ns = nrm_of(degO[n]);
    ushort4 s;
    s.x = f2bf(y0 * ns); s.y = f2bf(y1 * ns);
    s.z = f2bf(y2 * ns); s.w = f2bf(y3 * ns);
    *(ushort4*)(p2bf + (size_t)n * 64 + cb * 4) = s;
}

// -------- zero the per-row counters ------------------------------------------
__global__ void k_zcnt(int* __restrict__ colr, int N) {
    int i = blockIdx.x * 256 + threadIdx.x;
    if (i < N) colr[(size_t)i * CAPR] = 0;
}

// ------ phase A: proj1 (bf16) || {degO all + colr fill for d < NSPLIT} -------
template<int DIN, int DOUT, int RB, int KT>
__global__ void __launch_bounds__(256) k_combA(
        const float* __restrict__ x, const float* __restrict__ W,
        ushort_t* __restrict__ outbf, int N,
        const int* __restrict__ src, const int* __restrict__ dst,
        int* __restrict__ degO, int* __restrict__ colr,
        int E, int PB, int HTH, int NSPLIT) {
    constexpr int CG  = DOUT / 4;
    constexpr int RPP = 256 / CG;
    constexpr int R4  = RB / RPP;
    constexpr int K4T = KT / 4;
    __shared__ float4 wlds[KT * CG];
    __shared__ float4 xlds[RB * K4T];

    int bid = blockIdx.x, g = bid / 5, r = bid - g * 5;
    if (r == 4) {
        int i = g * 256 + (int)threadIdx.x;
        for (; i < E; i += HTH) {
            int s = src[i];
            int d = dst[i];
            atomicAdd(&degO[s], 1);
            if (d < NSPLIT) {
                int rk = atomicAdd(&colr[(size_t)d * CAPR], 1);
                if (rk < CAP) colr[(size_t)d * CAPR + 4 + rk] = s;
            }
        }
        return;
    }
    int pidx = g * 4 + r;
    if (pidx >= PB) return;
    int n0 = pidx * RB;
    proj_body<DIN, DOUT, RB, KT>(x, W, N, n0, wlds, xlds,
        [&](float4 (&acc)[R4], int rp, int cg) {
#pragma unroll
            for (int rr = 0; rr < R4; ++rr) {
                int n = n0 + rp + rr * RPP;
                if (n < N) {
                    ushort4 s;
                    s.x = f2bf(acc[rr].x); s.y = f2bf(acc[rr].y);
                    s.z = f2bf(acc[rr].z); s.w = f2bf(acc[rr].w);
                    *(ushort4*)(outbf + (size_t)n * DOUT + cg * 4) = s;
                }
            }
        });
}

// ------ phase B: FUSED gl1p2 n<NSPLIT || {colr fill for d >= NSPLIT} ---------
__global__ void __launch_bounds__(256) k_combB(
        const int* __restrict__ src, const int* __restrict__ dst,
        int* __restrict__ colr, const int* __restrict__ degO,
        const ushort_t* __restrict__ p1bf, const float* __restrict__ b1,
        const float* __restrict__ W2, ushort_t* __restrict__ p2bf,
        int NSPLIT, int E, int HTH) {
    __shared__ float w2s[128 * 64];   // 32 KB
    int bid = blockIdx.x, g = bid / 5, r = bid - g * 5;
    if (r == 4) {
        int i = g * 256 + (int)threadIdx.x;
        for (; i < E; i += HTH) {
            int d = dst[i];
            if (d >= NSPLIT) {
                int rk = atomicAdd(&colr[(size_t)d * CAPR], 1);
                if (rk < CAP) colr[(size_t)d * CAPR + 4 + rk] = src[i];
            }
        }
        return;
    }
#pragma unroll
    for (int j = 0; j < 8; ++j)
        gload_lds16((const float4*)W2 + j * 256 + threadIdx.x,
                    (float4*)w2s + j * 256 + threadIdx.x);
    __syncthreads();
    long t = ((long)(g * 4 + r)) * 256 + threadIdx.x;
    if (t >= (long)NSPLIT * 16) return;
    int n  = (int)(t >> 4);
    int cb = (int)(t & 15);
    int gb = (threadIdx.x & 63) & ~15;
    gl1p2_body(n, cb, gb, colr, degO, p1bf, b1, w2s, p2bf);
}

// -------- standalone FUSED gl1p2 for nodes [nlo, N) --------------------------
__global__ void __launch_bounds__(256) k_gl1p2(
        const int* __restrict__ colr, const int* __restrict__ degO,
        const ushort_t* __restrict__ p1bf, const float* __restrict__ b1,
        const float* __restrict__ W2, ushort_t* __restrict__ p2bf,
        int nlo, int N) {
    __shared__ float w2s[128 * 64];   // 32 KB
#pragma unroll
    for (int j = 0; j < 8; ++j)
        gload_lds16((const float4*)W2 + j * 256 + threadIdx.x,
                    (float4*)w2s + j * 256 + threadIdx.x);
    __syncthreads();
    long t = blockIdx.x * 256L + threadIdx.x;
    if (t >= (long)(N - nlo) * 16) return;
    int n  = nlo + (int)(t >> 4);
    int cb = (int)(t & 15);
    int gb = (threadIdx.x & 63) & ~15;
    gl1p2_body(n, cb, gb, colr, degO, p1bf, b1, w2s, p2bf);
}

// -------- L2 FUSED: bf16 gather (64) -> h2 = relu(sum*nD+b2) -> P3=(h2*nS)@W3 -
__global__ void __launch_bounds__(256) k_gather_fuse2(
        const int* __restrict__ colr, const int* __restrict__ degO,
        const ushort_t* __restrict__ p2bf, const float* __restrict__ b2,
        const float* __restrict__ W3, float* __restrict__ P3, int N) {
    constexpr int DOUT = 64;
    __shared__ float w3s[64 * 16];     // 4 KB
    ((float4*)w3s)[threadIdx.x] = ((const float4*)W3)[threadIdx.x];
    __syncthreads();

    long t = blockIdx.x * 256L + threadIdx.x;
    int n = (int)(t >> 3);
    bool valid = n < N;
    if (!valid) n = N - 1;
    int cb = (int)(t & 7);
    int lane = threadIdx.x & 63;
    int gb = lane & ~7;

    const int* cl = colr + (size_t)n * CAPR;
    int dgi = cl[0];
    int dg = dgi > CAP ? CAP : dgi;
    float acc[8];
#pragma unroll
    for (int k = 0; k < 8; ++k) acc[k] = 0.f;
    int i = 0;
    for (; i + 4 <= dg; i += 4) {
        int4 ss = *(const int4*)(cl + 4 + i);
        uint4 v0 = *(const uint4*)(p2bf + (size_t)ss.x * DOUT + cb * 8);
        uint4 v1 = *(const uint4*)(p2bf + (size_t)ss.y * DOUT + cb * 8);
        uint4 v2 = *(const uint4*)(p2bf + (size_t)ss.z * DOUT + cb * 8);
        uint4 v3 = *(const uint4*)(p2bf + (size_t)ss.w * DOUT + cb * 8);
        acc[0] += BFLO(v0.x) + BFLO(v1.x) + BFLO(v2.x) + BFLO(v3.x);
        acc[1] += BFHI(v0.x) + BFHI(v1.x) + BFHI(v2.x) + BFHI(v3.x);
        acc[2] += BFLO(v0.y) + BFLO(v1.y) + BFLO(v2.y) + BFLO(v3.y);
        acc[3] += BFHI(v0.y) + BFHI(v1.y) + BFHI(v2.y) + BFHI(v3.y);
        acc[4] += BFLO(v0.z) + BFLO(v1.z) + BFLO(v2.z) + BFLO(v3.z);
        acc[5] += BFHI(v0.z) + BFHI(v1.z) + BFHI(v2.z) + BFHI(v3.z);
        acc[6] += BFLO(v0.w) + BFLO(v1.w) + BFLO(v2.w) + BFLO(v3.w);
        acc[7] += BFHI(v0.w) + BFHI(v1.w) + BFHI(v2.w) + BFHI(v3.w);
    }
    for (; i < dg; ++i) {
        int s0 = cl[4 + i];
        uint4 v0 = *(const uint4*)(p2bf + (size_t)s0 * DOUT + cb * 8);
        acc[0] += BFLO(v0.x); acc[1] += BFHI(v0.x);
        acc[2] += BFLO(v0.y); acc[3] += BFHI(v0.y);
        acc[4] += BFLO(v0.z); acc[5] += BFHI(v0.z);
        acc[6] += BFLO(v0.w); acc[7] += BFHI(v0.w);
    }
    float nm = nrm_of(dgi);
    float ns = nrm_of(degO[n]);
    const float* bp = b2 + cb * 8;
    float o[8];
#pragma unroll
    for (int k = 0; k < 8; ++k)
        o[k] = fmaxf(fmaf(acc[k], nm, bp[k]), 0.f) * ns;
    float y0 = 0.f, y1 = 0.f;
#pragma unroll
    for (int k = 0; k < 64; ++k) {
        float v = __shfl(o[k & 7], gb + (k >> 3), 64);
        y0 = fmaf(v, w3s[k * 16 + 2 * cb], y0);
        y1 = fmaf(v, w3s[k * 16 + 2 * cb + 1], y1);
    }
    if (valid) *(float2*)(P3 + (size_t)n * 16 + 2 * cb) = make_float2(y0, y1);
}

// -------- L3: fp32 gather P3 (16) -> t4 = relu(sum*nD+b3)*nS -----------------
__global__ void __launch_bounds__(256) k_gather_l3(
        const int* __restrict__ colr, const int* __restrict__ degO,
        const float* __restrict__ proj, const float* __restrict__ bias,
        float* __restrict__ out, int N) {
    long t = blockIdx.x * 256L + threadIdx.x;
    if (t >= (long)N * 4) return;
    int n  = (int)(t >> 2);
    int cg = (int)(t & 3);
    const int* cl = colr + (size_t)n * CAPR;
    int dgi = cl[0];
    int dg = dgi > CAP ? CAP : dgi;
    float4 a0 = make_float4(0.f, 0.f, 0.f, 0.f);
    float4 a1 = make_float4(0.f, 0.f, 0.f, 0.f);
    float4 a2 = make_float4(0.f, 0.f, 0.f, 0.f);
    float4 a3 = make_float4(0.f, 0.f, 0.f, 0.f);
    int i = 0;
    for (; i + 4 <= dg; i += 4) {
        int4 ss = *(const int4*)(cl + 4 + i);
        float4 v0 = *(const float4*)(proj + (size_t)ss.x * 16 + cg * 4);
        float4 v1 = *(const float4*)(proj + (size_t)ss.y * 16 + cg * 4);
        float4 v2 = *(const float4*)(proj + (size_t)ss.z * 16 + cg * 4);
        float4 v3 = *(const float4*)(proj + (size_t)ss.w * 16 + cg * 4);
        a0.x += v0.x; a0.y += v0.y; a0.z += v0.z; a0.w += v0.w;
        a1.x += v1.x; a1.y += v1.y; a1.z += v1.z; a1.w += v1.w;
        a2.x += v2.x; a2.y += v2.y; a2.z += v2.z; a2.w += v2.w;
        a3.x += v3.x; a3.y += v3.y; a3.z += v3.z; a3.w += v3.w;
    }
    for (; i < dg; ++i) {
        int s0 = cl[4 + i];
        float4 v0 = *(const float4*)(proj + (size_t)s0 * 16 + cg * 4);
        a0.x += v0.x; a0.y += v0.y; a0.z += v0.z; a0.w += v0.w;
    }
    float4 s = make_float4(a0.x + a1.x + a2.x + a3.x, a0.y + a1.y + a2.y + a3.y,
                           a0.z + a1.z + a2.z + a3.z, a0.w + a1.w + a2.w + a3.w);
    float nm = nrm_of(dgi);
    float ns = nrm_of(degO[n]);
    float4 b = *(const float4*)(bias + cg * 4);
    float4 o;
    o.x = fmaxf(fmaf(s.x, nm, b.x), 0.f) * ns;
    o.y = fmaxf(fmaf(s.y, nm, b.y), 0.f) * ns;
    o.z = fmaxf(fmaf(s.z, nm, b.z), 0.f) * ns;
    o.w = fmaxf(fmaf(s.w, nm, b.w), 0.f) * ns;
    *(float4*)(out + (size_t)n * 16 + cg * 4) = o;
}

// -------- L4 FUSED: gather t4 (16) -> out = (agg@W4)*nD + b4 (40 wide) -------
__global__ void __launch_bounds__(256) k_gather_fuse4(
        const int* __restrict__ colr, const float* __restrict__ t4,
        const float* __restrict__ W4, const float* __restrict__ b4,
        float* __restrict__ out, int N) {
    __shared__ float w4s[16 * 40];
    __shared__ float b4s[40];
    for (int i = threadIdx.x; i < 160; i += 256)
        ((float4*)w4s)[i] = ((const float4*)W4)[i];
    if (threadIdx.x < 40) b4s[threadIdx.x] = b4[threadIdx.x];
    __syncthreads();

    long t = blockIdx.x * 256L + threadIdx.x;
    int n = (int)(t >> 2);
    bool valid = n < N;
    if (!valid) n = N - 1;
    int cg = (int)(t & 3);
    int lane = threadIdx.x & 63;
    int gb = lane & ~3;

    const int* cl = colr + (size_t)n * CAPR;
    int dgi = cl[0];
    int dg = dgi > CAP ? CAP : dgi;
    float4 a0 = make_float4(0.f, 0.f, 0.f, 0.f);
    float4 a1 = make_float4(0.f, 0.f, 0.f, 0.f);
    int i = 0;
    for (; i + 2 <= dg; i += 2) {
        int2 ss = *(const int2*)(cl + 4 + i);
        float4 v0 = *(const float4*)(t4 + (size_t)ss.x * 16 + cg * 4);
        float4 v1 = *(const float4*)(t4 + (size_t)ss.y * 16 + cg * 4);
        a0.x += v0.x; a0.y += v0.y; a0.z += v0.z; a0.w += v0.w;
        a1.x += v1.x; a1.y += v1.y; a1.z += v1.z; a1.w += v1.w;
    }
    if (i < dg) {
        int s0 = cl[4 + i];
        float4 v0 = *(const float4*)(t4 + (size_t)s0 * 16 + cg * 4);
        a0.x += v0.x; a0.y += v0.y; a0.z += v0.z; a0.w += v0.w;
    }
    float av[4] = { a0.x + a1.x, a0.y + a1.y, a0.z + a1.z, a0.w + a1.w };

    float y[10];
#pragma unroll
    for (int jj = 0; jj < 10; ++jj) y[jj] = 0.f;
#pragma unroll
    for (int k = 0; k < 16; ++k) {
        float v = __shfl(av[k & 3], gb + (k >> 2), 64);
        const float* wr = w4s + k * 40 + cg * 10;
#pragma unroll
        for (int jj = 0; jj < 10; ++jj) y[jj] = fmaf(v, wr[jj], y[jj]);
    }
    if (valid) {
        float nm = nrm_of(dgi);
        float* dp = out + (size_t)n * 40 + cg * 10;
        const float* bp = b4s + cg * 10;
#pragma unroll
        for (int jj = 0; jj < 10; ++jj) dp[jj] = fmaf(y[jj], nm, bp[jj]);
    }
}

static inline int cdiv(long a, int b) { return (int)((a + b - 1) / b); }

extern "C" void kernel_launch(void* const* d_in, const int* in_sizes, int n_in,
                              void* d_out, int out_size, void* d_ws, size_t ws_size,
                              hipStream_t stream) {
    const float* x   = (const float*)d_in[0];
    const int*   src = (const int*)d_in[1];
    const int*   dst = (const int*)d_in[2];
    const float* W1 = (const float*)d_in[3];  const float* b1 = (const float*)d_in[4];
    const float* W2 = (const float*)d_in[5];  const float* b2 = (const float*)d_in[6];
    const float* W3 = (const float*)d_in[7];  const float* b3 = (const float*)d_in[8];
    const float* W4 = (const float*)d_in[9];  const float* b4 = (const float*)d_in[10];

    const int N = in_sizes[0] / 256;
    const int E = in_sizes[1];
    const int NSPLIT = ((N / 2) + 63) / 64 * 64;   // f=0.5

    // ---- workspace layout (~79 MB) ----
    int* ws_i = (int*)d_ws;
    int* degO = ws_i;                          // [N]
    int* colr = ws_i + N;                      // [N*CAPR]
    float* fbase = (float*)(ws_i + N + (size_t)N * CAPR);
    ushort_t* p1bf = (ushort_t*)fbase;                      // N*128 bf16
    ushort_t* p2bf = (ushort_t*)(fbase + (size_t)N * 64);   // N*64 bf16
    float* P3 = fbase + (size_t)N * 96;        // N*16 f32
    float* t4 = fbase + (size_t)N * 112;       // N*16 f32

    int PB  = cdiv(N, 64);
    int G5A = cdiv(PB, 4);
    int HTHA = G5A * 256;

    long tB = (long)NSPLIT * 16;
    int G5B = cdiv(cdiv(tB, 256), 4);
    int HTHB = G5B * 256;

    // ---- init: degO=0, colr counters=0 ----
    hipMemsetAsync(degO, 0, (size_t)N * sizeof(int), stream);
    k_zcnt<<<cdiv(N, 256), 256, 0, stream>>>(colr, N);

    // ---- phase A: proj1 || degO-all + colr(d<NSPLIT) ----
    k_combA<256, 128, 64, 32><<<5 * G5A, 256, 0, stream>>>(
        x, W1, p1bf, N, src, dst, degO, colr, E, PB, HTHA, NSPLIT);

    // ---- phase B: FUSED gl1p2[0,NSPLIT) || colr[NSPLIT,N) ----
    k_combB<<<5 * G5B, 256, 0, stream>>>(
        src, dst, colr, degO, p1bf, b1, W2, p2bf, NSPLIT, E, HTHB);

    // ---- phase C: FUSED gl1p2 [NSPLIT, N) ----
    k_gl1p2<<<cdiv((long)(N - NSPLIT) * 16, 256), 256, 0, stream>>>(
        colr, degO, p1bf, b1, W2, p2bf, NSPLIT, N);

    // ---- L2 tail: FUSED gather P2 + P3 GEMM ----
    k_gather_fuse2<<<cdiv((long)N * 8, 256), 256, 0, stream>>>(
        colr, degO, p2bf, b2, W3, P3, N);

    // ---- L3: gather P3 -> t4 ----
    k_gather_l3<<<cdiv((long)N * 4, 256), 256, 0, stream>>>(
        colr, degO, P3, b3, t4, N);

    // ---- L4 FUSED: gather t4 + (agg@W4)*nD+b4 -> out ----
    k_gather_fuse4<<<cdiv((long)N * 4, 256), 256, 0, stream>>>(
        colr, t4, W4, b4, (float*)d_out, N);
}

// Round 19
// 332.721 us; speedup vs baseline: 1.0405x; 1.0405x over previous
//
#include <hip/hip_runtime.h>

// GCN 4 layers: N=100000, E=1600000, dims 256->128->64->16->40.
//  A: {proj1 P1=x@W1 bf16} || {degO all + degI/colp d<NSPLIT}   (f=0.5)
//  B: {FUSED gather_l1+proj_l2 n<NSPLIT} || {degI/colp d>=NSPLIT}
//  C: FUSED gather_l1+proj_l2 [NSPLIT,N)
//     (fusion: h1 row stays in the node's 16 threads' registers; P2=(h1@W2)*nS
//      via 16-step shfl-ring GEMM with W2 staged f32 in LDS; h1 NEVER hits memory.)
//  L2 tail: FUSED gather P2 + h2 + P3=(h2*nS)@W3 (W3 LDS, shfl)
//  L3: fp32 gather P3 -> t4;  L4: FUSED gather t4 + (agg@W4)*nD+b4 -> out
// Norms inline rsqrt(max(deg,1)). CAP=64 padded adjacency (Poisson(16)).
// [r19 = revert to proven r17 structure; r18's inline-counter row regressed:
//  gfx950 atomics are memory-side, co-locating store+atomic serializes them.]

typedef unsigned short ushort_t;
#define CAP 64

__device__ __forceinline__ void gload_lds16(const float4* g, float4* l) {
    __builtin_amdgcn_global_load_lds(
        (const __attribute__((address_space(1))) void*)g,
        (__attribute__((address_space(3))) void*)l, 16, 0, 0);
}

__device__ __forceinline__ ushort_t f2bf(float f) {
    unsigned u = __float_as_uint(f);
    u += 0x7FFFu + ((u >> 16) & 1u);          // RNE
    return (ushort_t)(u >> 16);
}
__device__ __forceinline__ float nrm_of(int d) {
    return rsqrtf((float)(d > 1 ? d : 1));
}
#define BFLO(u) __uint_as_float((u) << 16)
#define BFHI(u) __uint_as_float((u) & 0xffff0000u)

// ---------------- proj GEMM body for L1 (f32 in, global_load_lds staged) ------
template<int DIN, int DOUT, int RB, int KT, typename EPI>
__device__ __forceinline__ void proj_body(
        const float* __restrict__ in, const float* __restrict__ W,
        int N, int n0, float4* __restrict__ wlds, float4* __restrict__ xlds,
        EPI&& epi) {
    constexpr int CG  = DOUT / 4;
    constexpr int RPP = 256 / CG;
    constexpr int R4  = RB / RPP;
    constexpr int K4T = KT / 4;
    constexpr int NKT = DIN / KT;
    constexpr int XTILE = RB * K4T;
    constexpr int WTILE = KT * CG;

    const int tid  = threadIdx.x;
    const int wave = tid >> 6;
    const int lane = tid & 63;
    const int rp   = tid / CG;
    const int cg   = tid - rp * CG;

    float4 acc[R4];
#pragma unroll
    for (int r = 0; r < R4; ++r) acc[r] = make_float4(0.f, 0.f, 0.f, 0.f);

    for (int kt = 0; kt < NKT; ++kt) {
        const float4* wsrc = (const float4*)(W + (size_t)kt * KT * DOUT);
#pragma unroll
        for (int j = 0; j < WTILE / 256; ++j) {
            int base = j * 256 + wave * 64;
            gload_lds16(wsrc + base + lane, &wlds[base]);
        }
#pragma unroll
        for (int j = 0; j < XTILE / 256; ++j) {
            int base = j * 256 + wave * 64;
            int fi   = base + lane;
            int row  = fi / K4T;
            int k4   = fi - row * K4T;
            int k4s  = k4 ^ (row & (K4T - 1));
            int grow = n0 + row; if (grow >= N) grow = N - 1;
            const float4* gsrc = (const float4*)(in + (size_t)grow * DIN) + kt * K4T + k4s;
            gload_lds16(gsrc, &xlds[base]);
        }
        __syncthreads();
#pragma unroll 2
        for (int k4 = 0; k4 < K4T; ++k4) {
            float4 w0 = wlds[(k4 * 4 + 0) * CG + cg];
            float4 w1 = wlds[(k4 * 4 + 1) * CG + cg];
            float4 w2 = wlds[(k4 * 4 + 2) * CG + cg];
            float4 w3 = wlds[(k4 * 4 + 3) * CG + cg];
#pragma unroll
            for (int r = 0; r < R4; ++r) {
                int row = rp + r * RPP;
                float4 xv = xlds[row * K4T + (k4 ^ (row & (K4T - 1)))];
                acc[r].x = fmaf(xv.x, w0.x, acc[r].x);
                acc[r].y = fmaf(xv.x, w0.y, acc[r].y);
                acc[r].z = fmaf(xv.x, w0.z, acc[r].z);
                acc[r].w = fmaf(xv.x, w0.w, acc[r].w);
                acc[r].x = fmaf(xv.y, w1.x, acc[r].x);
                acc[r].y = fmaf(xv.y, w1.y, acc[r].y);
                acc[r].z = fmaf(xv.y, w1.z, acc[r].z);
                acc[r].w = fmaf(xv.y, w1.w, acc[r].w);
                acc[r].x = fmaf(xv.z, w2.x, acc[r].x);
                acc[r].y = fmaf(xv.z, w2.y, acc[r].y);
                acc[r].z = fmaf(xv.z, w2.z, acc[r].z);
                acc[r].w = fmaf(xv.z, w2.w, acc[r].w);
                acc[r].x = fmaf(xv.w, w3.x, acc[r].x);
                acc[r].y = fmaf(xv.w, w3.y, acc[r].y);
                acc[r].z = fmaf(xv.w, w3.z, acc[r].z);
                acc[r].w = fmaf(xv.w, w3.w, acc[r].w);
            }
        }
        __syncthreads();
    }
    epi(acc, rp, cg);
}

// ------ FUSED L1-gather + L2-proj body --------------------------------------
__device__ __forceinline__ void gl1p2_body(
        int n, int cb, int gb, const int* __restrict__ colp,
        const int* __restrict__ degO, const int* __restrict__ degI,
        const ushort_t* __restrict__ p1bf, const float* __restrict__ b1,
        const float* __restrict__ w2s, ushort_t* __restrict__ p2bf) {
    constexpr int DOUT = 128;
    const int* cl = colp + (size_t)n * CAP;
    int dgi = degI[n];
    int dg = dgi > CAP ? CAP : dgi;
    float acc[8];
#pragma unroll
    for (int k = 0; k < 8; ++k) acc[k] = 0.f;
    int i = 0;
    for (; i + 4 <= dg; i += 4) {
        int4 ss = *(const int4*)(cl + i);
        uint4 v0 = *(const uint4*)(p1bf + (size_t)ss.x * DOUT + cb * 8);
        uint4 v1 = *(const uint4*)(p1bf + (size_t)ss.y * DOUT + cb * 8);
        uint4 v2 = *(const uint4*)(p1bf + (size_t)ss.z * DOUT + cb * 8);
        uint4 v3 = *(const uint4*)(p1bf + (size_t)ss.w * DOUT + cb * 8);
        float n0 = nrm_of(degO[ss.x]), n1 = nrm_of(degO[ss.y]);
        float n2 = nrm_of(degO[ss.z]), n3 = nrm_of(degO[ss.w]);
        acc[0] = fmaf(n0, BFLO(v0.x), fmaf(n1, BFLO(v1.x), fmaf(n2, BFLO(v2.x), fmaf(n3, BFLO(v3.x), acc[0]))));
        acc[1] = fmaf(n0, BFHI(v0.x), fmaf(n1, BFHI(v1.x), fmaf(n2, BFHI(v2.x), fmaf(n3, BFHI(v3.x), acc[1]))));
        acc[2] = fmaf(n0, BFLO(v0.y), fmaf(n1, BFLO(v1.y), fmaf(n2, BFLO(v2.y), fmaf(n3, BFLO(v3.y), acc[2]))));
        acc[3] = fmaf(n0, BFHI(v0.y), fmaf(n1, BFHI(v1.y), fmaf(n2, BFHI(v2.y), fmaf(n3, BFHI(v3.y), acc[3]))));
        acc[4] = fmaf(n0, BFLO(v0.z), fmaf(n1, BFLO(v1.z), fmaf(n2, BFLO(v2.z), fmaf(n3, BFLO(v3.z), acc[4]))));
        acc[5] = fmaf(n0, BFHI(v0.z), fmaf(n1, BFHI(v1.z), fmaf(n2, BFHI(v2.z), fmaf(n3, BFHI(v3.z), acc[5]))));
        acc[6] = fmaf(n0, BFLO(v0.w), fmaf(n1, BFLO(v1.w), fmaf(n2, BFLO(v2.w), fmaf(n3, BFLO(v3.w), acc[6]))));
        acc[7] = fmaf(n0, BFHI(v0.w), fmaf(n1, BFHI(v1.w), fmaf(n2, BFHI(v2.w), fmaf(n3, BFHI(v3.w), acc[7]))));
    }
    for (; i < dg; ++i) {
        int s0 = cl[i];
        uint4 v0 = *(const uint4*)(p1bf + (size_t)s0 * DOUT + cb * 8);
        float ns0 = nrm_of(degO[s0]);
        acc[0] = fmaf(ns0, BFLO(v0.x), acc[0]);
        acc[1] = fmaf(ns0, BFHI(v0.x), acc[1]);
        acc[2] = fmaf(ns0, BFLO(v0.y), acc[2]);
        acc[3] = fmaf(ns0, BFHI(v0.y), acc[3]);
        acc[4] = fmaf(ns0, BFLO(v0.z), acc[4]);
        acc[5] = fmaf(ns0, BFHI(v0.z), acc[5]);
        acc[6] = fmaf(ns0, BFLO(v0.w), acc[6]);
        acc[7] = fmaf(ns0, BFHI(v0.w), acc[7]);
    }
    float nm = nrm_of(dgi);
    const float* bp = b1 + cb * 8;
    float o[8];
#pragma unroll
    for (int k = 0; k < 8; ++k) o[k] = fmaxf(fmaf(acc[k], nm, bp[k]), 0.f);

    // ---- P2 row: shfl-ring GEMM, cols cb*4..cb*4+3 ----
    float y0 = 0.f, y1 = 0.f, y2 = 0.f, y3 = 0.f;
    for (int k8 = 0; k8 < 16; ++k8) {
#pragma unroll
        for (int j = 0; j < 8; ++j) {
            float v = __shfl(o[j], gb + k8, 64);
            const float4 w = *(const float4*)(w2s + (k8 * 8 + j) * 64 + cb * 4);
            y0 = fmaf(v, w.x, y0);
            y1 = fmaf(v, w.y, y1);
            y2 = fmaf(v, w.z, y2);
            y3 = fmaf(v, w.w, y3);
        }
    }
    float ns = nrm_of(degO[n]);
    ushort4 s;
    s.x = f2bf(y0 * ns); s.y = f2bf(y1 * ns);
    s.z = f2bf(y2 * ns); s.w = f2bf(y3 * ns);
    *(ushort4*)(p2bf + (size_t)n * 64 + cb * 4) = s;
}

// ------ phase A: proj1 (bf16) || {degO all + degI/colp for d < NSPLIT} -------
template<int DIN, int DOUT, int RB, int KT>
__global__ void __launch_bounds__(256) k_combA(
        const float* __restrict__ x, const float* __restrict__ W,
        ushort_t* __restrict__ outbf, int N,
        const int* __restrict__ src, const int* __restrict__ dst,
        int* __restrict__ degO, int* __restrict__ degI,
        int* __restrict__ colp, int E, int PB, int HTH, int NSPLIT) {
    constexpr int CG  = DOUT / 4;
    constexpr int RPP = 256 / CG;
    constexpr int R4  = RB / RPP;
    constexpr int K4T = KT / 4;
    __shared__ float4 wlds[KT * CG];
    __shared__ float4 xlds[RB * K4T];

    int bid = blockIdx.x, g = bid / 5, r = bid - g * 5;
    if (r == 4) {
        int i = g * 256 + (int)threadIdx.x;
        for (; i < E; i += HTH) {
            int s = src[i];
            int d = dst[i];
            atomicAdd(&degO[s], 1);
            if (d < NSPLIT) {
                int rk = atomicAdd(&degI[d], 1);
                if (rk < CAP) colp[(size_t)d * CAP + rk] = s;
            }
        }
        return;
    }
    int pidx = g * 4 + r;
    if (pidx >= PB) return;
    int n0 = pidx * RB;
    proj_body<DIN, DOUT, RB, KT>(x, W, N, n0, wlds, xlds,
        [&](float4 (&acc)[R4], int rp, int cg) {
#pragma unroll
            for (int rr = 0; rr < R4; ++rr) {
                int n = n0 + rp + rr * RPP;
                if (n < N) {
                    ushort4 s;
                    s.x = f2bf(acc[rr].x); s.y = f2bf(acc[rr].y);
                    s.z = f2bf(acc[rr].z); s.w = f2bf(acc[rr].w);
                    *(ushort4*)(outbf + (size_t)n * DOUT + cg * 4) = s;
                }
            }
        });
}

// ------ phase B: FUSED gl1p2 n<NSPLIT || {degI/colp for d >= NSPLIT} ---------
__global__ void __launch_bounds__(256) k_combB(
        const int* __restrict__ src, const int* __restrict__ dst,
        int* __restrict__ degI, int* __restrict__ colp,
        const int* __restrict__ degO, const ushort_t* __restrict__ p1bf,
        const float* __restrict__ b1, const float* __restrict__ W2,
        ushort_t* __restrict__ p2bf, int NSPLIT, int E, int HTH) {
    __shared__ float w2s[128 * 64];   // 32 KB
    int bid = blockIdx.x, g = bid / 5, r = bid - g * 5;
    if (r == 4) {
        int i = g * 256 + (int)threadIdx.x;
        for (; i < E; i += HTH) {
            int d = dst[i];
            if (d >= NSPLIT) {
                int rk = atomicAdd(&degI[d], 1);
                if (rk < CAP) colp[(size_t)d * CAP + rk] = src[i];
            }
        }
        return;
    }
    // stage W2 (f32, 2048 float4)
#pragma unroll
    for (int j = 0; j < 8; ++j)
        gload_lds16((const float4*)W2 + j * 256 + threadIdx.x,
                    (float4*)w2s + j * 256 + threadIdx.x);
    __syncthreads();
    long t = ((long)(g * 4 + r)) * 256 + threadIdx.x;
    if (t >= (long)NSPLIT * 16) return;
    int n  = (int)(t >> 4);
    int cb = (int)(t & 15);
    int gb = (threadIdx.x & 63) & ~15;
    gl1p2_body(n, cb, gb, colp, degO, degI, p1bf, b1, w2s, p2bf);
}

// -------- standalone FUSED gl1p2 for nodes [nlo, N) --------------------------
__global__ void __launch_bounds__(256) k_gl1p2(
        const int* __restrict__ colp, const int* __restrict__ degO,
        const int* __restrict__ degI, const ushort_t* __restrict__ p1bf,
        const float* __restrict__ b1, const float* __restrict__ W2,
        ushort_t* __restrict__ p2bf, int nlo, int N) {
    __shared__ float w2s[128 * 64];   // 32 KB
#pragma unroll
    for (int j = 0; j < 8; ++j)
        gload_lds16((const float4*)W2 + j * 256 + threadIdx.x,
                    (float4*)w2s + j * 256 + threadIdx.x);
    __syncthreads();
    long t = blockIdx.x * 256L + threadIdx.x;
    if (t >= (long)(N - nlo) * 16) return;
    int n  = nlo + (int)(t >> 4);
    int cb = (int)(t & 15);
    int gb = (threadIdx.x & 63) & ~15;
    gl1p2_body(n, cb, gb, colp, degO, degI, p1bf, b1, w2s, p2bf);
}

// -------- L2 FUSED: bf16 gather (64) -> h2 = relu(sum*nD+b2) -> P3=(h2*nS)@W3 -
__global__ void __launch_bounds__(256) k_gather_fuse2(
        const int* __restrict__ colp, const int* __restrict__ degO,
        const int* __restrict__ degI, const ushort_t* __restrict__ p2bf,
        const float* __restrict__ b2, const float* __restrict__ W3,
        float* __restrict__ P3, int N) {
    constexpr int DOUT = 64;
    __shared__ float w3s[64 * 16];     // 4 KB
    ((float4*)w3s)[threadIdx.x] = ((const float4*)W3)[threadIdx.x];
    __syncthreads();

    long t = blockIdx.x * 256L + threadIdx.x;
    int n = (int)(t >> 3);
    bool valid = n < N;
    if (!valid) n = N - 1;
    int cb = (int)(t & 7);
    int lane = threadIdx.x & 63;
    int gb = lane & ~7;

    const int* cl = colp + (size_t)n * CAP;
    int dgi = degI[n];
    int dg = dgi > CAP ? CAP : dgi;
    float acc[8];
#pragma unroll
    for (int k = 0; k < 8; ++k) acc[k] = 0.f;
    int i = 0;
    for (; i + 4 <= dg; i += 4) {
        int4 ss = *(const int4*)(cl + i);
        uint4 v0 = *(const uint4*)(p2bf + (size_t)ss.x * DOUT + cb * 8);
        uint4 v1 = *(const uint4*)(p2bf + (size_t)ss.y * DOUT + cb * 8);
        uint4 v2 = *(const uint4*)(p2bf + (size_t)ss.z * DOUT + cb * 8);
        uint4 v3 = *(const uint4*)(p2bf + (size_t)ss.w * DOUT + cb * 8);
        acc[0] += BFLO(v0.x) + BFLO(v1.x) + BFLO(v2.x) + BFLO(v3.x);
        acc[1] += BFHI(v0.x) + BFHI(v1.x) + BFHI(v2.x) + BFHI(v3.x);
        acc[2] += BFLO(v0.y) + BFLO(v1.y) + BFLO(v2.y) + BFLO(v3.y);
        acc[3] += BFHI(v0.y) + BFHI(v1.y) + BFHI(v2.y) + BFHI(v3.y);
        acc[4] += BFLO(v0.z) + BFLO(v1.z) + BFLO(v2.z) + BFLO(v3.z);
        acc[5] += BFHI(v0.z) + BFHI(v1.z) + BFHI(v2.z) + BFHI(v3.z);
        acc[6] += BFLO(v0.w) + BFLO(v1.w) + BFLO(v2.w) + BFLO(v3.w);
        acc[7] += BFHI(v0.w) + BFHI(v1.w) + BFHI(v2.w) + BFHI(v3.w);
    }
    for (; i < dg; ++i) {
        int s0 = cl[i];
        uint4 v0 = *(const uint4*)(p2bf + (size_t)s0 * DOUT + cb * 8);
        acc[0] += BFLO(v0.x); acc[1] += BFHI(v0.x);
        acc[2] += BFLO(v0.y); acc[3] += BFHI(v0.y);
        acc[4] += BFLO(v0.z); acc[5] += BFHI(v0.z);
        acc[6] += BFLO(v0.w); acc[7] += BFHI(v0.w);
    }
    float nm = nrm_of(dgi);
    float ns = nrm_of(degO[n]);
    const float* bp = b2 + cb * 8;
    float o[8];
#pragma unroll
    for (int k = 0; k < 8; ++k)
        o[k] = fmaxf(fmaf(acc[k], nm, bp[k]), 0.f) * ns;
    float y0 = 0.f, y1 = 0.f;
#pragma unroll
    for (int k = 0; k < 64; ++k) {
        float v = __shfl(o[k & 7], gb + (k >> 3), 64);
        y0 = fmaf(v, w3s[k * 16 + 2 * cb], y0);
        y1 = fmaf(v, w3s[k * 16 + 2 * cb + 1], y1);
    }
    if (valid) *(float2*)(P3 + (size_t)n * 16 + 2 * cb) = make_float2(y0, y1);
}

// -------- L3: fp32 gather P3 (16) -> t4 = relu(sum*nD+b3)*nS -----------------
__global__ void __launch_bounds__(256) k_gather_l3(
        const int* __restrict__ colp, const int* __restrict__ degO,
        const int* __restrict__ degI, const float* __restrict__ proj,
        const float* __restrict__ bias, float* __restrict__ out, int N) {
    long t = blockIdx.x * 256L + threadIdx.x;
    if (t >= (long)N * 4) return;
    int n  = (int)(t >> 2);
    int cg = (int)(t & 3);
    const int* cl = colp + (size_t)n * CAP;
    int dgi = degI[n];
    int dg = dgi > CAP ? CAP : dgi;
    float4 a0 = make_float4(0.f, 0.f, 0.f, 0.f);
    float4 a1 = make_float4(0.f, 0.f, 0.f, 0.f);
    float4 a2 = make_float4(0.f, 0.f, 0.f, 0.f);
    float4 a3 = make_float4(0.f, 0.f, 0.f, 0.f);
    int i = 0;
    for (; i + 4 <= dg; i += 4) {
        int4 ss = *(const int4*)(cl + i);
        float4 v0 = *(const float4*)(proj + (size_t)ss.x * 16 + cg * 4);
        float4 v1 = *(const float4*)(proj + (size_t)ss.y * 16 + cg * 4);
        float4 v2 = *(const float4*)(proj + (size_t)ss.z * 16 + cg * 4);
        float4 v3 = *(const float4*)(proj + (size_t)ss.w * 16 + cg * 4);
        a0.x += v0.x; a0.y += v0.y; a0.z += v0.z; a0.w += v0.w;
        a1.x += v1.x; a1.y += v1.y; a1.z += v1.z; a1.w += v1.w;
        a2.x += v2.x; a2.y += v2.y; a2.z += v2.z; a2.w += v2.w;
        a3.x += v3.x; a3.y += v3.y; a3.z += v3.z; a3.w += v3.w;
    }
    for (; i < dg; ++i) {
        int s0 = cl[i];
        float4 v0 = *(const float4*)(proj + (size_t)s0 * 16 + cg * 4);
        a0.x += v0.x; a0.y += v0.y; a0.z += v0.z; a0.w += v0.w;
    }
    float4 s = make_float4(a0.x + a1.x + a2.x + a3.x, a0.y + a1.y + a2.y + a3.y,
                           a0.z + a1.z + a2.z + a3.z, a0.w + a1.w + a2.w + a3.w);
    float nm = nrm_of(dgi);
    float ns = nrm_of(degO[n]);
    float4 b = *(const float4*)(bias + cg * 4);
    float4 o;
    o.x = fmaxf(fmaf(s.x, nm, b.x), 0.f) * ns;
    o.y = fmaxf(fmaf(s.y, nm, b.y), 0.f) * ns;
    o.z = fmaxf(fmaf(s.z, nm, b.z), 0.f) * ns;
    o.w = fmaxf(fmaf(s.w, nm, b.w), 0.f) * ns;
    *(float4*)(out + (size_t)n * 16 + cg * 4) = o;
}

// -------- L4 FUSED: gather t4 (16) -> out = (agg@W4)*nD + b4 (40 wide) -------
__global__ void __launch_bounds__(256) k_gather_fuse4(
        const int* __restrict__ colp, const int* __restrict__ degI,
        const float* __restrict__ t4, const float* __restrict__ W4,
        const float* __restrict__ b4, float* __restrict__ out, int N) {
    __shared__ float w4s[16 * 40];
    __shared__ float b4s[40];
    for (int i = threadIdx.x; i < 160; i += 256)
        ((float4*)w4s)[i] = ((const float4*)W4)[i];
    if (threadIdx.x < 40) b4s[threadIdx.x] = b4[threadIdx.x];
    __syncthreads();

    long t = blockIdx.x * 256L + threadIdx.x;
    int n = (int)(t >> 2);
    bool valid = n < N;
    if (!valid) n = N - 1;
    int cg = (int)(t & 3);
    int lane = threadIdx.x & 63;
    int gb = lane & ~3;

    const int* cl = colp + (size_t)n * CAP;
    int dgi = degI[n];
    int dg = dgi > CAP ? CAP : dgi;
    float4 a0 = make_float4(0.f, 0.f, 0.f, 0.f);
    float4 a1 = make_float4(0.f, 0.f, 0.f, 0.f);
    int i = 0;
    for (; i + 2 <= dg; i += 2) {
        int2 ss = *(const int2*)(cl + i);
        float4 v0 = *(const float4*)(t4 + (size_t)ss.x * 16 + cg * 4);
        float4 v1 = *(const float4*)(t4 + (size_t)ss.y * 16 + cg * 4);
        a0.x += v0.x; a0.y += v0.y; a0.z += v0.z; a0.w += v0.w;
        a1.x += v1.x; a1.y += v1.y; a1.z += v1.z; a1.w += v1.w;
    }
    if (i < dg) {
        int s0 = cl[i];
        float4 v0 = *(const float4*)(t4 + (size_t)s0 * 16 + cg * 4);
        a0.x += v0.x; a0.y += v0.y; a0.z += v0.z; a0.w += v0.w;
    }
    float av[4] = { a0.x + a1.x, a0.y + a1.y, a0.z + a1.z, a0.w + a1.w };

    float y[10];
#pragma unroll
    for (int jj = 0; jj < 10; ++jj) y[jj] = 0.f;
#pragma unroll
    for (int k = 0; k < 16; ++k) {
        float v = __shfl(av[k & 3], gb + (k >> 2), 64);
        const float* wr = w4s + k * 40 + cg * 10;
#pragma unroll
        for (int jj = 0; jj < 10; ++jj) y[jj] = fmaf(v, wr[jj], y[jj]);
    }
    if (valid) {
        float nm = nrm_of(dgi);
        float* dp = out + (size_t)n * 40 + cg * 10;
        const float* bp = b4s + cg * 10;
#pragma unroll
        for (int jj = 0; jj < 10; ++jj) dp[jj] = fmaf(y[jj], nm, bp[jj]);
    }
}

static inline int cdiv(long a, int b) { return (int)((a + b - 1) / b); }

extern "C" void kernel_launch(void* const* d_in, const int* in_sizes, int n_in,
                              void* d_out, int out_size, void* d_ws, size_t ws_size,
                              hipStream_t stream) {
    const float* x   = (const float*)d_in[0];
    const int*   src = (const int*)d_in[1];
    const int*   dst = (const int*)d_in[2];
    const float* W1 = (const float*)d_in[3];  const float* b1 = (const float*)d_in[4];
    const float* W2 = (const float*)d_in[5];  const float* b2 = (const float*)d_in[6];
    const float* W3 = (const float*)d_in[7];  const float* b3 = (const float*)d_in[8];
    const float* W4 = (const float*)d_in[9];  const float* b4 = (const float*)d_in[10];

    const int N = in_sizes[0] / 256;
    const int E = in_sizes[1];
    const int NSPLIT = ((N / 2) + 63) / 64 * 64;   // f=0.5 (proven)

    // ---- workspace layout (~78 MB) ----
    int* ws_i = (int*)d_ws;
    int* degO   = ws_i;                        // [N]
    int* degI   = ws_i + N;                    // [N]
    int* colp   = ws_i + 2 * (size_t)N;        // [N*CAP]
    float* fbase = (float*)(ws_i + 2 * (size_t)N + (size_t)N * CAP);
    ushort_t* p1bf = (ushort_t*)fbase;                 // N*128 bf16 (N*64 f32)
    ushort_t* p2bf = (ushort_t*)(fbase + (size_t)N * 64);  // N*64 bf16 (N*32 f32)
    float* P3 = fbase + (size_t)N * 96;        // N*16 f32
    float* t4 = fbase + (size_t)N * 112;       // N*16 f32

    int PB  = cdiv(N, 64);
    int G5A = cdiv(PB, 4);
    int HTHA = G5A * 256;

    long tB = (long)NSPLIT * 16;
    int G5B = cdiv(cdiv(tB, 256), 4);
    int HTHB = G5B * 256;

    // ---- phase A: proj1 || degO-all + degI/colp(d<NSPLIT) ----
    hipMemsetAsync(degO, 0, 2 * (size_t)N * sizeof(int), stream);
    k_combA<256, 128, 64, 32><<<5 * G5A, 256, 0, stream>>>(
        x, W1, p1bf, N, src, dst, degO, degI, colp, E, PB, HTHA, NSPLIT);

    // ---- phase B: FUSED gl1p2[0,NSPLIT) || degI/colp[NSPLIT,N) ----
    k_combB<<<5 * G5B, 256, 0, stream>>>(
        src, dst, degI, colp, degO, p1bf, b1, W2, p2bf, NSPLIT, E, HTHB);

    // ---- phase C: FUSED gl1p2 [NSPLIT, N) ----
    k_gl1p2<<<cdiv((long)(N - NSPLIT) * 16, 256), 256, 0, stream>>>(
        colp, degO, degI, p1bf, b1, W2, p2bf, NSPLIT, N);

    // ---- L2 tail: FUSED gather P2 + P3 GEMM ----
    k_gather_fuse2<<<cdiv((long)N * 8, 256), 256, 0, stream>>>(
        colp, degO, degI, p2bf, b2, W3, P3, N);

    // ---- L3: gather P3 -> t4 ----
    k_gather_l3<<<cdiv((long)N * 4, 256), 256, 0, stream>>>(
        colp, degO, degI, P3, b3, t4, N);

    // ---- L4 FUSED: gather t4 + (agg@W4)*nD+b4 -> out ----
    k_gather_fuse4<<<cdiv((long)N * 4, 256), 256, 0, stream>>>(
        colp, degI, t4, W4, b4, (float*)d_out, N);
}